// Round 1
// baseline (43.641 us; speedup 1.0000x reference)
//
#include <hip/hip_runtime.h>
#include <math.h>

#define T_LEN 6000
#define B_ROWS 4096
#define PICK_WIN 20
#define BETA 25.0f

// ---------------------------------------------------------------------------
// K1: per-row L1 partial sum + first-index argmax of |target|.
// One block per row, 256 threads, float4 loads (row stride 24000B % 16 == 0,
// T/4 = 1500 exactly so no scalar tail).
// ---------------------------------------------------------------------------
__global__ __launch_bounds__(256) void row_pass1(const float* __restrict__ pred,
                                                 const float* __restrict__ target,
                                                 float* __restrict__ row_l1,
                                                 int* __restrict__ row_center) {
    const int row = blockIdx.x;
    const int tid = threadIdx.x;
    const float4* p4 = (const float4*)(pred + (size_t)row * T_LEN);
    const float4* t4 = (const float4*)(target + (size_t)row * T_LEN);

    float sum = 0.0f;
    float bestv = -1.0f;       // |t| >= 0, so always beaten
    int   besti = 0x7fffffff;

    // Within a thread, indices strictly increase -> strict '>' preserves
    // first-occurrence semantics.
    for (int i = tid; i < T_LEN / 4; i += 256) {
        float4 p = p4[i];
        float4 t = t4[i];
        sum += fabsf(p.x - t.x) + fabsf(p.y - t.y) +
               fabsf(p.z - t.z) + fabsf(p.w - t.w);
        const int base = i * 4;
        float a;
        a = fabsf(t.x); if (a > bestv) { bestv = a; besti = base;     }
        a = fabsf(t.y); if (a > bestv) { bestv = a; besti = base + 1; }
        a = fabsf(t.z); if (a > bestv) { bestv = a; besti = base + 2; }
        a = fabsf(t.w); if (a > bestv) { bestv = a; besti = base + 3; }
    }

    __shared__ float s_sum[256];
    __shared__ float s_val[256];
    __shared__ int   s_idx[256];
    s_sum[tid] = sum; s_val[tid] = bestv; s_idx[tid] = besti;
    __syncthreads();

    for (int off = 128; off > 0; off >>= 1) {
        if (tid < off) {
            s_sum[tid] += s_sum[tid + off];
            const float v  = s_val[tid + off];
            const int   ix = s_idx[tid + off];
            // larger value wins; on exact tie, smaller index wins (first max)
            if (v > s_val[tid] || (v == s_val[tid] && ix < s_idx[tid])) {
                s_val[tid] = v; s_idx[tid] = ix;
            }
        }
        __syncthreads();
    }

    if (tid == 0) {
        row_l1[row]     = s_sum[0];
        row_center[row] = s_idx[0];
    }
}

// ---------------------------------------------------------------------------
// K2: windowed soft-argmax for pred & target, one wave64 per row.
// Window = [max(0,c-20), min(T,c+20)), length <= 40 -> lanes 0..len-1 active.
// ---------------------------------------------------------------------------
__global__ __launch_bounds__(256) void pick_pass(const float* __restrict__ pred,
                                                 const float* __restrict__ target,
                                                 const int* __restrict__ row_center,
                                                 float* __restrict__ row_pick) {
    const int row  = blockIdx.x * 4 + (threadIdx.x >> 6);
    const int lane = threadIdx.x & 63;

    const int c = row_center[row];
    const int s = max(0, c - PICK_WIN);
    const int e = min(T_LEN, c + PICK_WIN);
    const int len = e - s;

    float ap = -INFINITY, at = -INFINITY;
    const float posf = (float)(s + lane);
    if (lane < len) {
        const size_t idx = (size_t)row * T_LEN + s + lane;
        ap = BETA * fabsf(pred[idx]);
        at = BETA * fabsf(target[idx]);
    }

    // wave-wide max (inactive lanes hold -inf)
    float mp = ap, mt = at;
    #pragma unroll
    for (int o = 32; o > 0; o >>= 1) {
        mp = fmaxf(mp, __shfl_xor(mp, o));
        mt = fmaxf(mt, __shfl_xor(mt, o));
    }

    float wp = 0.0f, wt = 0.0f, wpp = 0.0f, wtp = 0.0f;
    if (lane < len) {
        wp  = expf(ap - mp);
        wt  = expf(at - mt);
        wpp = wp * posf;
        wtp = wt * posf;
    }
    #pragma unroll
    for (int o = 32; o > 0; o >>= 1) {
        wp  += __shfl_xor(wp,  o);
        wt  += __shfl_xor(wt,  o);
        wpp += __shfl_xor(wpp, o);
        wtp += __shfl_xor(wtp, o);
    }

    if (lane == 0) {
        row_pick[row] = fabsf(wpp / wp - wtp / wt);
    }
}

// ---------------------------------------------------------------------------
// K3: deterministic final reduce + combine.
// ---------------------------------------------------------------------------
__global__ __launch_bounds__(256) void finalize(const float* __restrict__ row_l1,
                                                const float* __restrict__ row_pick,
                                                float* __restrict__ out) {
    __shared__ float s1[256], s2[256];
    const int tid = threadIdx.x;
    float a = 0.0f, b = 0.0f;
    for (int i = tid; i < B_ROWS; i += 256) {
        a += row_l1[i];
        b += row_pick[i];
    }
    s1[tid] = a; s2[tid] = b;
    __syncthreads();
    for (int off = 128; off > 0; off >>= 1) {
        if (tid < off) { s1[tid] += s1[tid + off]; s2[tid] += s2[tid + off]; }
        __syncthreads();
    }
    if (tid == 0) {
        const float loss = s1[0] / (float)((long long)B_ROWS * (long long)T_LEN);
        const float pick = (s2[0] / (float)B_ROWS) / (float)T_LEN;
        out[0] = loss + 0.1f * pick;
    }
}

extern "C" void kernel_launch(void* const* d_in, const int* in_sizes, int n_in,
                              void* d_out, int out_size, void* d_ws, size_t ws_size,
                              hipStream_t stream) {
    const float* pred   = (const float*)d_in[0];
    const float* target = (const float*)d_in[1];
    float* out = (float*)d_out;

    // workspace layout: [row_l1: 4096 f32][row_center: 4096 i32][row_pick: 4096 f32]
    float* row_l1     = (float*)d_ws;
    int*   row_center = (int*)(row_l1 + B_ROWS);
    float* row_pick   = (float*)(row_center + B_ROWS);

    row_pass1<<<B_ROWS, 256, 0, stream>>>(pred, target, row_l1, row_center);
    pick_pass<<<B_ROWS / 4, 256, 0, stream>>>(pred, target, row_center, row_pick);
    finalize<<<1, 256, 0, stream>>>(row_l1, row_pick, out);
}

// Round 2
// 40.231 us; speedup vs baseline: 1.0848x; 1.0848x over previous
//
#include <hip/hip_runtime.h>
#include <math.h>

#define T_LEN 6000
#define B_ROWS 4096
#define PICK_WIN 20
#define BETA 25.0f

// ---------------------------------------------------------------------------
// K1 (fused): per-row L1 sum + first-index argmax of |target| + windowed
// soft-argmax pick diff. One block per row, 256 threads.
// T/4 = 1500 float4s per array; thread k owns i = tid + 256*{0..5}
// (threads 0..219 get a 6th element: 1500 = 5*256 + 220).
// All 12 loads are issued back-to-back (independent) to maximize MLP —
// the previous rolled loop (VGPR=12) was latency-bound at 2.7 TB/s.
// ---------------------------------------------------------------------------
__global__ __launch_bounds__(256) void row_pass1(const float* __restrict__ pred,
                                                 const float* __restrict__ target,
                                                 float* __restrict__ row_l1,
                                                 float* __restrict__ row_pick) {
    const int row = blockIdx.x;
    const int tid = threadIdx.x;
    const float4* __restrict__ p4 = (const float4*)(pred + (size_t)row * T_LEN);
    const float4* __restrict__ t4 = (const float4*)(target + (size_t)row * T_LEN);

    float4 p[6], t[6];
    const int  i5   = tid + 5 * 256;
    const bool has6 = (i5 < T_LEN / 4);

    #pragma unroll
    for (int k = 0; k < 5; ++k) {
        p[k] = p4[tid + k * 256];
        t[k] = t4[tid + k * 256];
    }
    if (has6) { p[5] = p4[i5]; t[5] = t4[i5]; }

    float sum = 0.0f;
    float bestv = -1.0f;       // |t| >= 0, always beaten
    int   besti = 0x7fffffff;

    // Indices strictly increase within a thread -> '>' keeps first occurrence.
    #pragma unroll
    for (int k = 0; k < 6; ++k) {
        if (k == 5 && !has6) break;
        const int base = (tid + k * 256) * 4;
        const float4 pp = p[k], tt = t[k];
        sum += fabsf(pp.x - tt.x) + fabsf(pp.y - tt.y) +
               fabsf(pp.z - tt.z) + fabsf(pp.w - tt.w);
        float a;
        a = fabsf(tt.x); if (a > bestv) { bestv = a; besti = base;     }
        a = fabsf(tt.y); if (a > bestv) { bestv = a; besti = base + 1; }
        a = fabsf(tt.z); if (a > bestv) { bestv = a; besti = base + 2; }
        a = fabsf(tt.w); if (a > bestv) { bestv = a; besti = base + 3; }
    }

    __shared__ float s_sum[256];
    __shared__ float s_val[256];
    __shared__ int   s_idx[256];
    s_sum[tid] = sum; s_val[tid] = bestv; s_idx[tid] = besti;
    __syncthreads();

    for (int off = 128; off > 0; off >>= 1) {
        if (tid < off) {
            s_sum[tid] += s_sum[tid + off];
            const float v  = s_val[tid + off];
            const int   ix = s_idx[tid + off];
            // larger wins; exact tie -> smaller index (first max, like argmax)
            if (v > s_val[tid] || (v == s_val[tid] && ix < s_idx[tid])) {
                s_val[tid] = v; s_idx[tid] = ix;
            }
        }
        __syncthreads();
    }

    // ---- fused pick: wave 0 does the <=40-wide soft-argmax (data is L2-hot)
    if (tid < 64) {
        const int c   = s_idx[0];
        const int s   = max(0, c - PICK_WIN);
        const int e   = min(T_LEN, c + PICK_WIN);
        const int len = e - s;

        float ap = -INFINITY, at = -INFINITY;
        const float posf = (float)(s + tid);
        if (tid < len) {
            const size_t idx = (size_t)row * T_LEN + s + tid;
            ap = BETA * fabsf(pred[idx]);
            at = BETA * fabsf(target[idx]);
        }

        float mp = ap, mt = at;
        #pragma unroll
        for (int o = 32; o > 0; o >>= 1) {
            mp = fmaxf(mp, __shfl_xor(mp, o));
            mt = fmaxf(mt, __shfl_xor(mt, o));
        }

        float wp = 0.0f, wt = 0.0f, wpp = 0.0f, wtp = 0.0f;
        if (tid < len) {
            wp  = expf(ap - mp);
            wt  = expf(at - mt);
            wpp = wp * posf;
            wtp = wt * posf;
        }
        #pragma unroll
        for (int o = 32; o > 0; o >>= 1) {
            wp  += __shfl_xor(wp,  o);
            wt  += __shfl_xor(wt,  o);
            wpp += __shfl_xor(wpp, o);
            wtp += __shfl_xor(wtp, o);
        }

        if (tid == 0) {
            row_l1[row]   = s_sum[0];
            row_pick[row] = fabsf(wpp / wp - wtp / wt);
        }
    }
}

// ---------------------------------------------------------------------------
// K3: deterministic final reduce + combine.
// ---------------------------------------------------------------------------
__global__ __launch_bounds__(256) void finalize(const float* __restrict__ row_l1,
                                                const float* __restrict__ row_pick,
                                                float* __restrict__ out) {
    __shared__ float s1[256], s2[256];
    const int tid = threadIdx.x;
    float a = 0.0f, b = 0.0f;
    for (int i = tid; i < B_ROWS; i += 256) {
        a += row_l1[i];
        b += row_pick[i];
    }
    s1[tid] = a; s2[tid] = b;
    __syncthreads();
    for (int off = 128; off > 0; off >>= 1) {
        if (tid < off) { s1[tid] += s1[tid + off]; s2[tid] += s2[tid + off]; }
        __syncthreads();
    }
    if (tid == 0) {
        const float loss = s1[0] / (float)((long long)B_ROWS * (long long)T_LEN);
        const float pick = (s2[0] / (float)B_ROWS) / (float)T_LEN;
        out[0] = loss + 0.1f * pick;
    }
}

extern "C" void kernel_launch(void* const* d_in, const int* in_sizes, int n_in,
                              void* d_out, int out_size, void* d_ws, size_t ws_size,
                              hipStream_t stream) {
    const float* pred   = (const float*)d_in[0];
    const float* target = (const float*)d_in[1];
    float* out = (float*)d_out;

    // workspace layout: [row_l1: 4096 f32][row_pick: 4096 f32]
    float* row_l1   = (float*)d_ws;
    float* row_pick = row_l1 + B_ROWS;

    row_pass1<<<B_ROWS, 256, 0, stream>>>(pred, target, row_l1, row_pick);
    finalize<<<1, 256, 0, stream>>>(row_l1, row_pick, out);
}